// Round 6
// baseline (262.611 us; speedup 1.0000x reference)
//
#include <hip/hip_runtime.h>
#include <hip/hip_bf16.h>

#define WW 20
#define NW 8192         // 64*128 words
#define VOCAB 256
#define EE 64
#define HH 256
#define K3 768          // 3*HH
#define NTAP 9          // 1 + 3 + 5
#define UNIT 2304       // ushorts per vocab unit = 4608 B

typedef short bf16x8 __attribute__((ext_vector_type(8)));
typedef float f32x4  __attribute__((ext_vector_type(4)));

__device__ __forceinline__ ushort f2bs(float x) {
    __hip_bfloat16 h = __float2bfloat16(x);
    union { __hip_bfloat16 h; ushort u; } c; c.h = h; return c.u;
}
__device__ __forceinline__ float blo(unsigned u) {
    union { unsigned i; float f; } c; c.i = u << 16; return c.f;
}
__device__ __forceinline__ float bhi(unsigned u) {
    union { unsigned i; float f; } c; c.i = u & 0xffff0000u; return c.f;
}
__device__ __forceinline__ unsigned pack2(float lo, float hi) {
    return (unsigned)f2bs(lo) | ((unsigned)f2bs(hi) << 16);
}

#define SET2(d, w) { d[0] = blo(w); d[1] = bhi(w); }
#define ADD2(d, w) { d[0] += blo(w); d[1] += bhi(w); }
#define MAX2(m, s) { m[0] = fmaxf(m[0], s[0]); m[1] = fmaxf(m[1], s[1]); }

// ---------------------------------------------------------------------------
// P3 layout (per vocab v, 4608 B = 2304 ushorts), h-half o in {0,1}:
//   half block o*1152 ushorts. Within half (h-local l = h - 128o):
//     chunks c=0..3 (256 ushorts each): [u=l>>1][4 ushorts]:
//        {tap2c@h=2u, tap2c@2u+1, tap2c+1@2u, tap2c+1@2u+1}
//     tap8 region at +1024 (128 ushorts): [l] = tap8@h
// One (wave,char) = 4x dwordx2 + 1x dword, all off one scalar base.
// ---------------------------------------------------------------------------

// K0: prep. blocks 0..575: wTp[e][j] f32 (j = P3 column order);
//          blocks 576..767: lw f32 -> bf16.
__global__ __launch_bounds__(256) void prep(
        const float* __restrict__ w1,
        const float* __restrict__ w3,
        const float* __restrict__ w5,
        const float* __restrict__ lw,
        float* __restrict__ wTp,
        ushort* __restrict__ lwb) {
    const int bid = blockIdx.x;
    if (bid < 576) {
        int idx = bid * 256 + threadIdx.x;      // = e*2304 + j, 147456 total
        int e = idx / UNIT;
        int j = idx - e * UNIT;
        int o  = j / 1152;
        int jh = j - o * 1152;
        int tap, h;
        if (jh < 1024) {
            int c = jh >> 8, q = jh & 255, u = q >> 2, p = q & 3;
            tap = 2*c + (p >> 1);
            h   = o*128 + 2*u + (p & 1);
        } else { tap = 8; h = o*128 + (jh - 1024); }
        float v;
        if (tap == 0)      v = w1[h*EE + e];
        else if (tap <= 3) v = w3[(h*EE + e)*3 + (tap-1)];
        else               v = w5[(h*EE + e)*5 + (tap-4)];
        wTp[idx] = v;
    } else {
        int i = ((bid - 576) * 256 + threadIdx.x) * 4;
        float4 v = *(const float4*)(lw + i);
        ushort4 o4;
        o4.x = f2bs(v.x); o4.y = f2bs(v.y); o4.z = f2bs(v.z); o4.w = f2bs(v.w);
        *(ushort4*)(lwb + i) = o4;
    }
}

// K1: P3[v][j] = sum_e emb[v][e] * wTp[e][j]. 4 vocab rows per block,
// grid (64, 9) x 256 thr. Coalesced streaming reads/writes.
__global__ __launch_bounds__(256) void build_tables(
        const float* __restrict__ emb,
        const float* __restrict__ wTp,
        ushort* __restrict__ P3) {
    __shared__ float emb_s[4][EE];
    const int v0 = blockIdx.x * 4;
    const int j  = blockIdx.y * 256 + threadIdx.x;
    const int t  = threadIdx.x;
    emb_s[t >> 6][t & 63] = emb[v0*EE + t];
    __syncthreads();

    float a0 = 0.f, a1 = 0.f, a2 = 0.f, a3 = 0.f;
    const float* wp = wTp + j;
    #pragma unroll 8
    for (int e = 0; e < EE; ++e) {
        float w = wp[e * UNIT];
        a0 += emb_s[0][e] * w; a1 += emb_s[1][e] * w;
        a2 += emb_s[2][e] * w; a3 += emb_s[3][e] * w;
    }
    P3[(size_t)(v0+0)*UNIT + j] = f2bs(a0);
    P3[(size_t)(v0+1)*UNIT + j] = f2bs(a1);
    P3[(size_t)(v0+2)*UNIT + j] = f2bs(a2);
    P3[(size_t)(v0+3)*UNIT + j] = f2bs(a3);
}

// ---------------------------------------------------------------------------
// K2: conv+relu+maxpool, sliding-window. Wave = (word, h-half): lane owns
// h = o*128 + 2*lane + {0,1}. 2 words per 256-thr block, grid NW/2.
// Chars: one vector load + v_readlane -> SGPRs; per-char loads are
// saddr + {lane*8 | lane*4} with immediate chunk offsets.
// Bias after max (max(s)+b == max(s+b)); ReLU at the end.
// ---------------------------------------------------------------------------
__global__ __launch_bounds__(256, 8) void conv_pool(
        const int* __restrict__ chars,
        const ushort* __restrict__ P3,
        const float* __restrict__ b1,
        const float* __restrict__ b3,
        const float* __restrict__ b5,
        ushort* __restrict__ outs) {
    const int tid  = threadIdx.x;
    const int wave = tid >> 6, lane = tid & 63;
    const int n    = blockIdx.x * 2 + (wave >> 1);
    const int o    = wave & 1;

    // wave-uniform chars -> SGPRs
    int cv = chars[n * WW + (lane < WW ? lane : WW - 1)];
    int c[WW];
    #pragma unroll
    for (int j = 0; j < WW; ++j) c[j] = __builtin_amdgcn_readlane(cv, j);

    const ushort* base = P3 + o * 1152;

    float acc3[3][2], acc5[5][2], m1[2], m3[2], m5[2];
    acc3[0][0]=0.f; acc3[0][1]=0.f;
    acc5[0][0]=0.f; acc5[0][1]=0.f; acc5[1][0]=0.f; acc5[1][1]=0.f;
    m1[0]=-1e30f; m1[1]=-1e30f; m3[0]=-1e30f; m3[1]=-1e30f;
    m5[0]=-1e30f; m5[1]=-1e30f;

    uint2 q[2][4]; unsigned t8[2];
    {   // preload char 0
        const ushort* p = base + (size_t)c[0] * UNIT;
        #pragma unroll
        for (int i = 0; i < 4; ++i) q[0][i] = *(const uint2*)(p + i*256 + lane*4);
        t8[0] = *(const unsigned*)(p + 1024 + lane*2);
    }

    #pragma unroll
    for (int j = 0; j < WW; ++j) {
        const int cur = j & 1, nxt = cur ^ 1;
        if (j + 1 < WW) {   // prefetch char j+1
            const ushort* p = base + (size_t)c[j+1] * UNIT;
            #pragma unroll
            for (int i = 0; i < 4; ++i) q[nxt][i] = *(const uint2*)(p + i*256 + lane*4);
            t8[nxt] = *(const unsigned*)(p + 1024 + lane*2);
        }
        uint2 q0 = q[cur][0], q1 = q[cur][1], q2 = q[cur][2], q3 = q[cur][3];
        unsigned e8 = t8[cur];

        // conv1: tap0 -> position j
        m1[0] = fmaxf(m1[0], blo(q0.x)); m1[1] = fmaxf(m1[1], bhi(q0.x));
        // conv3: char j tap(1+tau) -> p = j+1-tau
        if (j + 1 < WW) SET2(acc3[(j+1)%3], q0.y)          // tap1, fresh p=j+1
        ADD2(acc3[j%3], q1.x)                               // tap2, p=j
        if (j >= 1) { ADD2(acc3[(j-1)%3], q1.y)             // tap3, p=j-1
                      MAX2(m3, acc3[(j-1)%3]) }             // p=j-1 complete
        // conv5: char j tap(4+tau) -> p = j+2-tau
        if (j + 2 < WW) SET2(acc5[(j+2)%5], q2.x)          // tap4, fresh p=j+2
        if (j + 1 < WW) ADD2(acc5[(j+1)%5], q2.y)          // tap5, p=j+1
        ADD2(acc5[j%5], q3.x)                               // tap6, p=j
        if (j >= 1) ADD2(acc5[(j-1)%5], q3.y)               // tap7, p=j-1
        if (j >= 2) { ADD2(acc5[(j-2)%5], e8)               // tap8, p=j-2
                      MAX2(m5, acc5[(j-2)%5]) }             // p=j-2 complete
    }
    MAX2(m3, acc3[(WW-1)%3])                                // p=19
    MAX2(m5, acc5[(WW-2)%5])                                // p=18
    MAX2(m5, acc5[(WW-1)%5])                                // p=19

    const int h0 = o*128 + lane*2;
    float2 bb1 = *(const float2*)(b1 + h0);
    float2 bb3 = *(const float2*)(b3 + h0);
    float2 bb5 = *(const float2*)(b5 + h0);
    unsigned* op = (unsigned*)(outs + (size_t)n * K3 + h0);
    op[0*(HH/2)] = pack2(fmaxf(m1[0]+bb1.x, 0.f), fmaxf(m1[1]+bb1.y, 0.f));
    op[1*(HH/2)] = pack2(fmaxf(m3[0]+bb3.x, 0.f), fmaxf(m3[1]+bb3.y, 0.f));
    op[2*(HH/2)] = pack2(fmaxf(m5[0]+bb5.x, 0.f), fmaxf(m5[1]+bb5.y, 0.f));
}

// ---------------------------------------------------------------------------
// K3: out = outs @ lw^T + lb via MFMA 16x16x32. 16m x 32n per wave,
// grid (512, 8) = 4096 single-wave blocks (16 waves/CU). Double-buffered
// fragments, fully unrolled K.
// A[m][k]: m=lane&15, k=quad*8+j. B[k][n]=lw[n][k]: n=lane&15, k=quad*8+j.
// C/D: col=lane&15, row=quad*4+reg.
// ---------------------------------------------------------------------------
__global__ __launch_bounds__(64) void gemm_out(
        const ushort* __restrict__ outs,   // [8192][768] bf16
        const ushort* __restrict__ lwb,    // [256][768] bf16
        const float* __restrict__ lb,
        float* __restrict__ out) {
    const int lane = threadIdx.x;
    const int m0 = blockIdx.x * 16;
    const int n0 = blockIdx.y * 32;
    const int mrow = lane & 15, quad = lane >> 4;

    f32x4 acc0 = (f32x4){0,0,0,0}, acc1 = (f32x4){0,0,0,0};
    const ushort* ap = outs + (size_t)(m0 + mrow) * K3 + quad * 8;
    const ushort* bp = lwb  + (size_t)(n0 + mrow) * K3 + quad * 8;

    bf16x8 a  = *(const bf16x8*)ap;
    bf16x8 b0 = *(const bf16x8*)bp;
    bf16x8 b1 = *(const bf16x8*)(bp + 16*K3);

    #pragma unroll
    for (int it = 0; it < K3/32; ++it) {
        const int kn = (it + 1 < K3/32) ? (it + 1) * 32 : 0;
        bf16x8 an  = *(const bf16x8*)(ap + kn);
        bf16x8 b0n = *(const bf16x8*)(bp + kn);
        bf16x8 b1n = *(const bf16x8*)(bp + 16*K3 + kn);
        acc0 = __builtin_amdgcn_mfma_f32_16x16x32_bf16(a, b0, acc0, 0, 0, 0);
        acc1 = __builtin_amdgcn_mfma_f32_16x16x32_bf16(a, b1, acc1, 0, 0, 0);
        a = an; b0 = b0n; b1 = b1n;
    }

    #pragma unroll
    for (int nn = 0; nn < 2; ++nn) {
        const f32x4 acc = nn ? acc1 : acc0;
        int ncol = n0 + nn*16 + mrow;
        float lbv = lb[ncol];
        #pragma unroll
        for (int r = 0; r < 4; ++r)
            out[(size_t)(m0 + quad*4 + r)*HH + ncol] = acc[r] + lbv;
    }
}

// ---------------------------------------------------------------------------
extern "C" void kernel_launch(void* const* d_in, const int* in_sizes, int n_in,
                              void* d_out, int out_size, void* d_ws, size_t ws_size,
                              hipStream_t stream) {
    const int*   chars = (const int*)d_in[0];
    const float* emb   = (const float*)d_in[1];
    const float* w1    = (const float*)d_in[2];
    const float* b1    = (const float*)d_in[3];
    const float* w3    = (const float*)d_in[4];
    const float* b3    = (const float*)d_in[5];
    const float* w5    = (const float*)d_in[6];
    const float* b5    = (const float*)d_in[7];
    const float* lw    = (const float*)d_in[8];
    const float* lb    = (const float*)d_in[9];

    // ws: P3 [256][2304] bf16 (1.18MB) | wTp [64][2304] f32 (0.59MB)
    //   | outs [8192][768] bf16 (12.6MB) | lwb [256][768] bf16 (0.39MB)
    ushort* P3   = (ushort*)d_ws;
    float*  wTp  = (float*)(P3 + VOCAB * UNIT);
    ushort* outs = (ushort*)(wTp + EE * UNIT);
    ushort* lwb  = outs + (size_t)NW * K3;

    prep<<<768, 256, 0, stream>>>(w1, w3, w5, lw, wTp, lwb);
    build_tables<<<dim3(VOCAB/4, NTAP), 256, 0, stream>>>(emb, wTp, P3);
    conv_pool<<<NW/2, 256, 0, stream>>>(chars, P3, b1, b3, b5, outs);
    gemm_out<<<dim3(NW/16, HH/32), 64, 0, stream>>>(outs, lwb, lb, (float*)d_out);
}

// Round 8
// 161.368 us; speedup vs baseline: 1.6274x; 1.6274x over previous
//
#include <hip/hip_runtime.h>
#include <hip/hip_bf16.h>

#define WW 20
#define NW 8192         // 64*128 words
#define VOCAB 256
#define EE 64
#define HH 256
#define K3 768          // 3*HH
#define NTAP 9          // 1 + 3 + 5
#define UNIT 2304       // ushorts per vocab unit = 4608 B

typedef short bf16x8 __attribute__((ext_vector_type(8)));
typedef float f32x4  __attribute__((ext_vector_type(4)));

__device__ __forceinline__ ushort f2bs(float x) {
    __hip_bfloat16 h = __float2bfloat16(x);
    union { __hip_bfloat16 h; ushort u; } c; c.h = h; return c.u;
}
__device__ __forceinline__ float blo(unsigned u) {
    union { unsigned i; float f; } c; c.i = u << 16; return c.f;
}
__device__ __forceinline__ float bhi(unsigned u) {
    union { unsigned i; float f; } c; c.i = u & 0xffff0000u; return c.f;
}
__device__ __forceinline__ unsigned pack2(float lo, float hi) {
    return (unsigned)f2bs(lo) | ((unsigned)f2bs(hi) << 16);
}

#define SET2(d, w) { d[0] = blo(w); d[1] = bhi(w); }
#define ADD2(d, w) { d[0] += blo(w); d[1] += bhi(w); }
#define MAX2(m, s) { m[0] = fmaxf(m[0], s[0]); m[1] = fmaxf(m[1], s[1]); }

// ---------------------------------------------------------------------------
// P3 layout (per vocab v, 4608 B = 2304 ushorts), h-half o in {0,1}:
//   half block o*1152 ushorts. Within half (h-local l = h - 128o):
//     chunks c=0..3 (256 ushorts each): [u=l>>1][4 ushorts]:
//        {tap2c@h=2u, tap2c@2u+1, tap2c+1@2u, tap2c+1@2u+1}
//     tap8 region at +1024 (128 ushorts): [l] = tap8@h
// One (wave,char) = 4x dwordx2 + 1x dword, all off one scalar base.
// ---------------------------------------------------------------------------

// K0: prep. blocks 0..575: wTp[e][j] f32 (j = P3 column order);
//          blocks 576..767: lw f32 -> bf16.
__global__ __launch_bounds__(256) void prep(
        const float* __restrict__ w1,
        const float* __restrict__ w3,
        const float* __restrict__ w5,
        const float* __restrict__ lw,
        float* __restrict__ wTp,
        ushort* __restrict__ lwb) {
    const int bid = blockIdx.x;
    if (bid < 576) {
        int idx = bid * 256 + threadIdx.x;      // = e*2304 + j, 147456 total
        int e = idx / UNIT;
        int j = idx - e * UNIT;
        int o  = j / 1152;
        int jh = j - o * 1152;
        int tap, h;
        if (jh < 1024) {
            int c = jh >> 8, q = jh & 255, u = q >> 2, p = q & 3;
            tap = 2*c + (p >> 1);
            h   = o*128 + 2*u + (p & 1);
        } else { tap = 8; h = o*128 + (jh - 1024); }
        float v;
        if (tap == 0)      v = w1[h*EE + e];
        else if (tap <= 3) v = w3[(h*EE + e)*3 + (tap-1)];
        else               v = w5[(h*EE + e)*5 + (tap-4)];
        wTp[idx] = v;
    } else {
        int i = ((bid - 576) * 256 + threadIdx.x) * 4;
        float4 v = *(const float4*)(lw + i);
        ushort4 o4;
        o4.x = f2bs(v.x); o4.y = f2bs(v.y); o4.z = f2bs(v.z); o4.w = f2bs(v.w);
        *(ushort4*)(lwb + i) = o4;
    }
}

// K1: P3[v][j] = sum_e emb[v][e] * wTp[e][j]. 4 vocab rows per block,
// grid (64, 9) x 256 thr. Coalesced streaming reads/writes.
__global__ __launch_bounds__(256) void build_tables(
        const float* __restrict__ emb,
        const float* __restrict__ wTp,
        ushort* __restrict__ P3) {
    __shared__ float emb_s[4][EE];
    const int v0 = blockIdx.x * 4;
    const int j  = blockIdx.y * 256 + threadIdx.x;
    const int t  = threadIdx.x;
    emb_s[t >> 6][t & 63] = emb[v0*EE + t];
    __syncthreads();

    float a0 = 0.f, a1 = 0.f, a2 = 0.f, a3 = 0.f;
    const float* wp = wTp + j;
    #pragma unroll 8
    for (int e = 0; e < EE; ++e) {
        float w = wp[e * UNIT];
        a0 += emb_s[0][e] * w; a1 += emb_s[1][e] * w;
        a2 += emb_s[2][e] * w; a3 += emb_s[3][e] * w;
    }
    P3[(size_t)(v0+0)*UNIT + j] = f2bs(a0);
    P3[(size_t)(v0+1)*UNIT + j] = f2bs(a1);
    P3[(size_t)(v0+2)*UNIT + j] = f2bs(a2);
    P3[(size_t)(v0+3)*UNIT + j] = f2bs(a3);
}

// ---------------------------------------------------------------------------
// K2: conv+relu+maxpool, sliding-window. Wave = (word, h-half): lane owns
// h = o*128 + 2*lane + {0,1}. 2 words per 256-thr block, grid NW/2.
// Chars: one vector load + v_readlane -> SGPRs; per-char loads are
// saddr + {lane*8 | lane*4} with immediate chunk offsets.
// Explicit 1-deep prefetch (R4/R5/R6-proven structure). NO forced
// min-occupancy: R6's (256,8) capped VGPR at 64 and spilled ~680 MB of
// scratch traffic per dispatch (FETCH 249 MB / WRITE 434 MB). Natural
// allocation ~60-70 VGPR -> 7-8 waves/SIMD without spill.
// Bias after max (max(s)+b == max(s+b)); ReLU at the end.
// ---------------------------------------------------------------------------
__global__ __launch_bounds__(256) void conv_pool(
        const int* __restrict__ chars,
        const ushort* __restrict__ P3,
        const float* __restrict__ b1,
        const float* __restrict__ b3,
        const float* __restrict__ b5,
        ushort* __restrict__ outs) {
    const int tid  = threadIdx.x;
    const int wave = tid >> 6, lane = tid & 63;
    const int n    = blockIdx.x * 2 + (wave >> 1);
    const int o    = wave & 1;

    // wave-uniform chars -> SGPRs
    int cv = chars[n * WW + (lane < WW ? lane : WW - 1)];
    int c[WW];
    #pragma unroll
    for (int j = 0; j < WW; ++j) c[j] = __builtin_amdgcn_readlane(cv, j);

    const ushort* base = P3 + o * 1152;

    float acc3[3][2], acc5[5][2], m1[2], m3[2], m5[2];
    acc3[0][0]=0.f; acc3[0][1]=0.f;
    acc5[0][0]=0.f; acc5[0][1]=0.f; acc5[1][0]=0.f; acc5[1][1]=0.f;
    m1[0]=-1e30f; m1[1]=-1e30f; m3[0]=-1e30f; m3[1]=-1e30f;
    m5[0]=-1e30f; m5[1]=-1e30f;

    uint2 q[2][4]; unsigned t8[2];
    {   // preload char 0
        const ushort* p = base + (size_t)c[0] * UNIT;
        #pragma unroll
        for (int i = 0; i < 4; ++i) q[0][i] = *(const uint2*)(p + i*256 + lane*4);
        t8[0] = *(const unsigned*)(p + 1024 + lane*2);
    }

    #pragma unroll
    for (int j = 0; j < WW; ++j) {
        const int cur = j & 1, nxt = cur ^ 1;
        if (j + 1 < WW) {   // prefetch char j+1
            const ushort* p = base + (size_t)c[j+1] * UNIT;
            #pragma unroll
            for (int i = 0; i < 4; ++i) q[nxt][i] = *(const uint2*)(p + i*256 + lane*4);
            t8[nxt] = *(const unsigned*)(p + 1024 + lane*2);
        }
        uint2 q0 = q[cur][0], q1 = q[cur][1], q2 = q[cur][2], q3 = q[cur][3];
        unsigned e8 = t8[cur];

        // conv1: tap0 -> position j
        m1[0] = fmaxf(m1[0], blo(q0.x)); m1[1] = fmaxf(m1[1], bhi(q0.x));
        // conv3: char j tap(1+tau) -> p = j+1-tau
        if (j + 1 < WW) SET2(acc3[(j+1)%3], q0.y)          // tap1, fresh p=j+1
        ADD2(acc3[j%3], q1.x)                               // tap2, p=j
        if (j >= 1) { ADD2(acc3[(j-1)%3], q1.y)             // tap3, p=j-1
                      MAX2(m3, acc3[(j-1)%3]) }             // p=j-1 complete
        // conv5: char j tap(4+tau) -> p = j+2-tau
        if (j + 2 < WW) SET2(acc5[(j+2)%5], q2.x)          // tap4, fresh p=j+2
        if (j + 1 < WW) ADD2(acc5[(j+1)%5], q2.y)          // tap5, p=j+1
        ADD2(acc5[j%5], q3.x)                               // tap6, p=j
        if (j >= 1) ADD2(acc5[(j-1)%5], q3.y)               // tap7, p=j-1
        if (j >= 2) { ADD2(acc5[(j-2)%5], e8)               // tap8, p=j-2
                      MAX2(m5, acc5[(j-2)%5]) }             // p=j-2 complete
    }
    MAX2(m3, acc3[(WW-1)%3])                                // p=19
    MAX2(m5, acc5[(WW-2)%5])                                // p=18
    MAX2(m5, acc5[(WW-1)%5])                                // p=19

    const int h0 = o*128 + lane*2;
    float2 bb1 = *(const float2*)(b1 + h0);
    float2 bb3 = *(const float2*)(b3 + h0);
    float2 bb5 = *(const float2*)(b5 + h0);
    unsigned* op = (unsigned*)(outs + (size_t)n * K3 + h0);
    op[0*(HH/2)] = pack2(fmaxf(m1[0]+bb1.x, 0.f), fmaxf(m1[1]+bb1.y, 0.f));
    op[1*(HH/2)] = pack2(fmaxf(m3[0]+bb3.x, 0.f), fmaxf(m3[1]+bb3.y, 0.f));
    op[2*(HH/2)] = pack2(fmaxf(m5[0]+bb5.x, 0.f), fmaxf(m5[1]+bb5.y, 0.f));
}

// ---------------------------------------------------------------------------
// K3: out = outs @ lw^T + lb via MFMA 16x16x32. 16m x 32n per wave,
// grid (512, 8) = 4096 single-wave blocks (16 waves/CU). Double-buffered
// fragments, fully unrolled K.
// A[m][k]: m=lane&15, k=quad*8+j. B[k][n]=lw[n][k]: n=lane&15, k=quad*8+j.
// C/D: col=lane&15, row=quad*4+reg.
// ---------------------------------------------------------------------------
__global__ __launch_bounds__(64) void gemm_out(
        const ushort* __restrict__ outs,   // [8192][768] bf16
        const ushort* __restrict__ lwb,    // [256][768] bf16
        const float* __restrict__ lb,
        float* __restrict__ out) {
    const int lane = threadIdx.x;
    const int m0 = blockIdx.x * 16;
    const int n0 = blockIdx.y * 32;
    const int mrow = lane & 15, quad = lane >> 4;

    f32x4 acc0 = (f32x4){0,0,0,0}, acc1 = (f32x4){0,0,0,0};
    const ushort* ap = outs + (size_t)(m0 + mrow) * K3 + quad * 8;
    const ushort* bp = lwb  + (size_t)(n0 + mrow) * K3 + quad * 8;

    bf16x8 a  = *(const bf16x8*)ap;
    bf16x8 b0 = *(const bf16x8*)bp;
    bf16x8 b1 = *(const bf16x8*)(bp + 16*K3);

    #pragma unroll
    for (int it = 0; it < K3/32; ++it) {
        const int kn = (it + 1 < K3/32) ? (it + 1) * 32 : 0;
        bf16x8 an  = *(const bf16x8*)(ap + kn);
        bf16x8 b0n = *(const bf16x8*)(bp + kn);
        bf16x8 b1n = *(const bf16x8*)(bp + 16*K3 + kn);
        acc0 = __builtin_amdgcn_mfma_f32_16x16x32_bf16(a, b0, acc0, 0, 0, 0);
        acc1 = __builtin_amdgcn_mfma_f32_16x16x32_bf16(a, b1, acc1, 0, 0, 0);
        a = an; b0 = b0n; b1 = b1n;
    }

    #pragma unroll
    for (int nn = 0; nn < 2; ++nn) {
        const f32x4 acc = nn ? acc1 : acc0;
        int ncol = n0 + nn*16 + mrow;
        float lbv = lb[ncol];
        #pragma unroll
        for (int r = 0; r < 4; ++r)
            out[(size_t)(m0 + quad*4 + r)*HH + ncol] = acc[r] + lbv;
    }
}

// ---------------------------------------------------------------------------
extern "C" void kernel_launch(void* const* d_in, const int* in_sizes, int n_in,
                              void* d_out, int out_size, void* d_ws, size_t ws_size,
                              hipStream_t stream) {
    const int*   chars = (const int*)d_in[0];
    const float* emb   = (const float*)d_in[1];
    const float* w1    = (const float*)d_in[2];
    const float* b1    = (const float*)d_in[3];
    const float* w3    = (const float*)d_in[4];
    const float* b3    = (const float*)d_in[5];
    const float* w5    = (const float*)d_in[6];
    const float* b5    = (const float*)d_in[7];
    const float* lw    = (const float*)d_in[8];
    const float* lb    = (const float*)d_in[9];

    // ws: P3 [256][2304] bf16 (1.18MB) | wTp [64][2304] f32 (0.59MB)
    //   | outs [8192][768] bf16 (12.6MB) | lwb [256][768] bf16 (0.39MB)
    ushort* P3   = (ushort*)d_ws;
    float*  wTp  = (float*)(P3 + VOCAB * UNIT);
    ushort* outs = (ushort*)(wTp + EE * UNIT);
    ushort* lwb  = outs + (size_t)NW * K3;

    prep<<<768, 256, 0, stream>>>(w1, w3, w5, lw, wTp, lwb);
    build_tables<<<dim3(VOCAB/4, NTAP), 256, 0, stream>>>(emb, wTp, P3);
    conv_pool<<<NW/2, 256, 0, stream>>>(chars, P3, b1, b3, b5, outs);
    gemm_out<<<dim3(NW/16, HH/32), 64, 0, stream>>>(outs, lwb, lb, (float*)d_out);
}

// Round 9
// 160.454 us; speedup vs baseline: 1.6367x; 1.0057x over previous
//
#include <hip/hip_runtime.h>
#include <hip/hip_bf16.h>

#define WW 20
#define NW 8192         // 64*128 words
#define VOCAB 256
#define EE 64
#define HH 256
#define K3 768          // 3*HH
#define UNIT4 2560      // ushorts per vocab unit (P4) = 256 h * 10 (9 taps + pad)

typedef short bf16x8 __attribute__((ext_vector_type(8)));
typedef float f32x4  __attribute__((ext_vector_type(4)));

__device__ __forceinline__ ushort f2bs(float x) {
    __hip_bfloat16 h = __float2bfloat16(x);
    union { __hip_bfloat16 h; ushort u; } c; c.h = h; return c.u;
}
__device__ __forceinline__ float blo(unsigned u) {
    union { unsigned i; float f; } c; c.i = u << 16; return c.f;
}
__device__ __forceinline__ float bhi(unsigned u) {
    union { unsigned i; float f; } c; c.i = u & 0xffff0000u; return c.f;
}

// ---------------------------------------------------------------------------
// P4 layout: [v][h][tap] with 10 ushorts per h (taps 0..8 + 1 pad) = 20 B/h,
// 5120 B per vocab. A (wave,char) for lane-owned h costs exactly 2 loads:
// dwordx4 @ h*20 (taps 0..7) + dword @ h*20+16 (tap8+pad), both 4B-aligned,
// off one scalar per-char base. 64 lanes span 1280 contiguous bytes.
// ---------------------------------------------------------------------------

// K0: prep. blocks 0..639: wTp[e][j] f32, j in P4 column order (j=h*10+tap,
// tap==9 -> 0). blocks 640..831: lw f32 -> bf16.
__global__ __launch_bounds__(256) void prep(
        const float* __restrict__ w1,
        const float* __restrict__ w3,
        const float* __restrict__ w5,
        const float* __restrict__ lw,
        float* __restrict__ wTp,
        ushort* __restrict__ lwb) {
    const int bid = blockIdx.x;
    if (bid < 640) {
        int idx = bid * 256 + threadIdx.x;      // = e*2560 + j, 163840 total
        int e = idx / UNIT4;
        int j = idx - e * UNIT4;
        int h = j / 10;
        int tap = j - h * 10;
        float v = 0.f;
        if (tap == 0)      v = w1[h*EE + e];
        else if (tap <= 3) v = w3[(h*EE + e)*3 + (tap-1)];
        else if (tap <= 8) v = w5[(h*EE + e)*5 + (tap-4)];
        wTp[idx] = v;
    } else {
        int i = ((bid - 640) * 256 + threadIdx.x) * 4;
        float4 v = *(const float4*)(lw + i);
        ushort4 o4;
        o4.x = f2bs(v.x); o4.y = f2bs(v.y); o4.z = f2bs(v.z); o4.w = f2bs(v.w);
        *(ushort4*)(lwb + i) = o4;
    }
}

// K1: P4[v][j] = sum_e emb[v][e] * wTp[e][j]. 4 vocab rows per block,
// grid (64, 10) x 256 thr. Coalesced streaming reads/writes.
__global__ __launch_bounds__(256) void build_tables(
        const float* __restrict__ emb,
        const float* __restrict__ wTp,
        ushort* __restrict__ P4) {
    __shared__ float emb_s[4][EE];
    const int v0 = blockIdx.x * 4;
    const int j  = blockIdx.y * 256 + threadIdx.x;
    const int t  = threadIdx.x;
    emb_s[t >> 6][t & 63] = emb[v0*EE + t];
    __syncthreads();

    float a0 = 0.f, a1 = 0.f, a2 = 0.f, a3 = 0.f;
    const float* wp = wTp + j;
    #pragma unroll 8
    for (int e = 0; e < EE; ++e) {
        float w = wp[e * UNIT4];
        a0 += emb_s[0][e] * w; a1 += emb_s[1][e] * w;
        a2 += emb_s[2][e] * w; a3 += emb_s[3][e] * w;
    }
    P4[(size_t)(v0+0)*UNIT4 + j] = f2bs(a0);
    P4[(size_t)(v0+1)*UNIT4 + j] = f2bs(a1);
    P4[(size_t)(v0+2)*UNIT4 + j] = f2bs(a2);
    P4[(size_t)(v0+3)*UNIT4 + j] = f2bs(a3);
}

// ---------------------------------------------------------------------------
// K2: conv+relu+maxpool, sliding-window. Block = 1 word (4 waves), wave =
// h-quarter o, lane owns h = o*64+lane. Chars via one vector load +
// v_readlane -> SGPRs; per char: scalar base + h*20 voffset, 2 loads.
// Explicit 1-deep prefetch (proven R4-R8). Live state ~40 VGPR -> under the
// 64-VGPR allocation cliff -> 8 waves/SIMD (R8 at 72 VGPR fell to the
// 4-wave class; m69: waves halve at vgpr=64).
// Bias after max (max(s)+b == max(s+b)); ReLU at the end.
// ---------------------------------------------------------------------------
__global__ __launch_bounds__(256) void conv_pool(
        const int* __restrict__ chars,
        const ushort* __restrict__ P4,
        const float* __restrict__ b1,
        const float* __restrict__ b3,
        const float* __restrict__ b5,
        ushort* __restrict__ outs) {
    const int tid  = threadIdx.x;
    const int wave = tid >> 6, lane = tid & 63;
    const int n    = blockIdx.x;
    const int h    = wave * 64 + lane;
    const int hb   = h * 20;                    // byte offset within a unit

    // wave-uniform chars -> SGPRs
    int cv = chars[n * WW + (lane < WW ? lane : WW - 1)];
    int c[WW];
    #pragma unroll
    for (int j = 0; j < WW; ++j) c[j] = __builtin_amdgcn_readlane(cv, j);

    float acc3[3], acc5[5], m1, m3, m5;
    acc3[0] = 0.f; acc5[0] = 0.f; acc5[1] = 0.f;
    m1 = -1e30f; m3 = -1e30f; m5 = -1e30f;

    uint4 q[2]; unsigned t8[2];
    {   // preload char 0
        const char* p = (const char*)P4 + (size_t)c[0] * 5120;
        q[0]  = *(const uint4*)(p + hb);
        t8[0] = *(const unsigned*)(p + hb + 16);
    }

    #pragma unroll
    for (int j = 0; j < WW; ++j) {
        const int cur = j & 1, nxt = cur ^ 1;
        if (j + 1 < WW) {   // prefetch char j+1
            const char* p = (const char*)P4 + (size_t)c[j+1] * 5120;
            q[nxt]  = *(const uint4*)(p + hb);
            t8[nxt] = *(const unsigned*)(p + hb + 16);
        }
        uint4 qq = q[cur];
        float t0 = blo(qq.x), t1 = bhi(qq.x), t2 = blo(qq.y), t3 = bhi(qq.y);
        float t4 = blo(qq.z), t5 = bhi(qq.z), t6 = blo(qq.w), t7 = bhi(qq.w);
        float t8v = blo(t8[cur]);

        // conv1: tap0 -> position j
        m1 = fmaxf(m1, t0);
        // conv3: char j tap(1+tau) -> p = j+1-tau
        if (j + 1 < WW) acc3[(j+1)%3] = t1;           // fresh p=j+1
        acc3[j%3] += t2;                               // p=j
        if (j >= 1) { acc3[(j-1)%3] += t3;             // p=j-1 complete
                      m3 = fmaxf(m3, acc3[(j-1)%3]); }
        // conv5: char j tap(4+tau) -> p = j+2-tau
        if (j + 2 < WW) acc5[(j+2)%5] = t4;           // fresh p=j+2
        if (j + 1 < WW) acc5[(j+1)%5] += t5;          // p=j+1
        acc5[j%5] += t6;                               // p=j
        if (j >= 1) acc5[(j-1)%5] += t7;               // p=j-1
        if (j >= 2) { acc5[(j-2)%5] += t8v;            // p=j-2 complete
                      m5 = fmaxf(m5, acc5[(j-2)%5]); }
    }
    m3 = fmaxf(m3, acc3[(WW-1)%3]);                    // p=19
    m5 = fmaxf(m5, acc5[(WW-2)%5]);                    // p=18
    m5 = fmaxf(m5, acc5[(WW-1)%5]);                    // p=19

    float v1 = fmaxf(m1 + b1[h], 0.f);
    float v3 = fmaxf(m3 + b3[h], 0.f);
    float v5 = fmaxf(m5 + b5[h], 0.f);
    ushort* op = outs + (size_t)n * K3 + h;
    op[0*HH] = f2bs(v1);
    op[1*HH] = f2bs(v3);
    op[2*HH] = f2bs(v5);
}

// ---------------------------------------------------------------------------
// K3: out = outs @ lw^T + lb via MFMA 16x16x32. 16m x 32n per wave,
// grid (512, 8) = 4096 single-wave blocks. Double-buffered fragments,
// fully unrolled K.
// A[m][k]: m=lane&15, k=quad*8+j. B[k][n]=lw[n][k]: n=lane&15, k=quad*8+j.
// C/D: col=lane&15, row=quad*4+reg.
// ---------------------------------------------------------------------------
__global__ __launch_bounds__(64) void gemm_out(
        const ushort* __restrict__ outs,   // [8192][768] bf16
        const ushort* __restrict__ lwb,    // [256][768] bf16
        const float* __restrict__ lb,
        float* __restrict__ out) {
    const int lane = threadIdx.x;
    const int m0 = blockIdx.x * 16;
    const int n0 = blockIdx.y * 32;
    const int mrow = lane & 15, quad = lane >> 4;

    f32x4 acc0 = (f32x4){0,0,0,0}, acc1 = (f32x4){0,0,0,0};
    const ushort* ap = outs + (size_t)(m0 + mrow) * K3 + quad * 8;
    const ushort* bp = lwb  + (size_t)(n0 + mrow) * K3 + quad * 8;

    bf16x8 a  = *(const bf16x8*)ap;
    bf16x8 b0 = *(const bf16x8*)bp;
    bf16x8 b1 = *(const bf16x8*)(bp + 16*K3);

    #pragma unroll
    for (int it = 0; it < K3/32; ++it) {
        const int kn = (it + 1 < K3/32) ? (it + 1) * 32 : 0;
        bf16x8 an  = *(const bf16x8*)(ap + kn);
        bf16x8 b0n = *(const bf16x8*)(bp + kn);
        bf16x8 b1n = *(const bf16x8*)(bp + 16*K3 + kn);
        acc0 = __builtin_amdgcn_mfma_f32_16x16x32_bf16(a, b0, acc0, 0, 0, 0);
        acc1 = __builtin_amdgcn_mfma_f32_16x16x32_bf16(a, b1, acc1, 0, 0, 0);
        a = an; b0 = b0n; b1 = b1n;
    }

    #pragma unroll
    for (int nn = 0; nn < 2; ++nn) {
        const f32x4 acc = nn ? acc1 : acc0;
        int ncol = n0 + nn*16 + mrow;
        float lbv = lb[ncol];
        #pragma unroll
        for (int r = 0; r < 4; ++r)
            out[(size_t)(m0 + quad*4 + r)*HH + ncol] = acc[r] + lbv;
    }
}

// ---------------------------------------------------------------------------
extern "C" void kernel_launch(void* const* d_in, const int* in_sizes, int n_in,
                              void* d_out, int out_size, void* d_ws, size_t ws_size,
                              hipStream_t stream) {
    const int*   chars = (const int*)d_in[0];
    const float* emb   = (const float*)d_in[1];
    const float* w1    = (const float*)d_in[2];
    const float* b1    = (const float*)d_in[3];
    const float* w3    = (const float*)d_in[4];
    const float* b3    = (const float*)d_in[5];
    const float* w5    = (const float*)d_in[6];
    const float* b5    = (const float*)d_in[7];
    const float* lw    = (const float*)d_in[8];
    const float* lb    = (const float*)d_in[9];

    // ws: P4 [256][2560] bf16 (1.31MB) | wTp [64][2560] f32 (0.66MB)
    //   | outs [8192][768] bf16 (12.6MB) | lwb [256][768] bf16 (0.39MB)
    ushort* P4   = (ushort*)d_ws;
    float*  wTp  = (float*)(P4 + VOCAB * UNIT4);
    ushort* outs = (ushort*)(wTp + EE * UNIT4);
    ushort* lwb  = outs + (size_t)NW * K3;

    prep<<<832, 256, 0, stream>>>(w1, w3, w5, lw, wTp, lwb);
    build_tables<<<dim3(VOCAB/4, 10), 256, 0, stream>>>(emb, wTp, P4);
    conv_pool<<<NW, 256, 0, stream>>>(chars, P4, b1, b3, b5, outs);
    gemm_out<<<dim3(NW/16, HH/32), 64, 0, stream>>>(outs, lwb, lb, (float*)d_out);
}

// Round 10
// 134.445 us; speedup vs baseline: 1.9533x; 1.1935x over previous
//
#include <hip/hip_runtime.h>
#include <hip/hip_bf16.h>

#define WW 20
#define NW 8192         // 64*128 words
#define VOCAB 256
#define EE 64
#define HH 256
#define K3 768          // 3*HH
#define UNIT 2304       // ushorts per vocab unit (P5) = 4608 B, no pad

typedef short bf16x8 __attribute__((ext_vector_type(8)));
typedef float f32x4  __attribute__((ext_vector_type(4)));

__device__ __forceinline__ ushort f2bs(float x) {
    __hip_bfloat16 h = __float2bfloat16(x);
    union { __hip_bfloat16 h; ushort u; } c; c.h = h; return c.u;
}
__device__ __forceinline__ float blo(unsigned u) {
    union { unsigned i; float f; } c; c.i = u << 16; return c.f;
}
__device__ __forceinline__ float bhi(unsigned u) {
    union { unsigned i; float f; } c; c.i = u & 0xffff0000u; return c.f;
}
__device__ __forceinline__ float bs2f(ushort u) {
    union { unsigned i; float f; } c; c.i = ((unsigned)u) << 16; return c.f;
}

// ---------------------------------------------------------------------------
// P5 layout (per vocab v, 2304 ushorts = 4608 B): 32 slices s of 144 B:
//   [hl 0..7][taps 0..7] (8 x 16 B rows), then [tap8 for hl 0..7] (16 B).
//   j = s*72 + r;  r<64: tap=r&7, h=s*8+(r>>3);  r>=64: tap=8, h=s*8+(r-64).
// conv blocks copy one 144-B slice row per v into LDS (fully 16-B aligned).
// ---------------------------------------------------------------------------

// K0: prep. blocks 0..575: wTp[e][j] f32 (P5 column order);
//          blocks 576..767: lw f32 -> bf16.
__global__ __launch_bounds__(256) void prep(
        const float* __restrict__ w1,
        const float* __restrict__ w3,
        const float* __restrict__ w5,
        const float* __restrict__ lw,
        float* __restrict__ wTp,
        ushort* __restrict__ lwb) {
    const int bid = blockIdx.x;
    if (bid < 576) {
        int idx = bid * 256 + threadIdx.x;      // = e*2304 + j, 147456 total
        int e = idx / UNIT;
        int j = idx - e * UNIT;
        int s = j / 72, r = j - s * 72;
        int tap, h;
        if (r < 64) { tap = r & 7; h = s*8 + (r >> 3); }
        else        { tap = 8;     h = s*8 + (r - 64); }
        float v;
        if (tap == 0)      v = w1[h*EE + e];
        else if (tap <= 3) v = w3[(h*EE + e)*3 + (tap-1)];
        else               v = w5[(h*EE + e)*5 + (tap-4)];
        wTp[idx] = v;
    } else {
        int i = ((bid - 576) * 256 + threadIdx.x) * 4;
        float4 v = *(const float4*)(lw + i);
        ushort4 o4;
        o4.x = f2bs(v.x); o4.y = f2bs(v.y); o4.z = f2bs(v.z); o4.w = f2bs(v.w);
        *(ushort4*)(lwb + i) = o4;
    }
}

// K1: P5[v][j] = sum_e emb[v][e] * wTp[e][j]. 4 vocab rows per block,
// grid (64, 9) x 256 thr. Coalesced streaming reads/writes.
__global__ __launch_bounds__(256) void build_tables(
        const float* __restrict__ emb,
        const float* __restrict__ wTp,
        ushort* __restrict__ P5) {
    __shared__ float emb_s[4][EE];
    const int v0 = blockIdx.x * 4;
    const int j  = blockIdx.y * 256 + threadIdx.x;
    const int t  = threadIdx.x;
    emb_s[t >> 6][t & 63] = emb[v0*EE + t];
    __syncthreads();

    float a0 = 0.f, a1 = 0.f, a2 = 0.f, a3 = 0.f;
    const float* wp = wTp + j;
    #pragma unroll 8
    for (int e = 0; e < EE; ++e) {
        float w = wp[e * UNIT];
        a0 += emb_s[0][e] * w; a1 += emb_s[1][e] * w;
        a2 += emb_s[2][e] * w; a3 += emb_s[3][e] * w;
    }
    P5[(size_t)(v0+0)*UNIT + j] = f2bs(a0);
    P5[(size_t)(v0+1)*UNIT + j] = f2bs(a1);
    P5[(size_t)(v0+2)*UNIT + j] = f2bs(a2);
    P5[(size_t)(v0+3)*UNIT + j] = f2bs(a3);
}

// ---------------------------------------------------------------------------
// K2: conv+relu+maxpool, LDS-staged table. Block = (word-group g: 128 words,
// h-slice s: 8 h). Stage: table slice (256 v x 144 B = 36 KB, per-v 16-B
// aligned rows; a wave's 64 ds_read_b128 lanes tile all 32 banks exactly
// 2x = conflict-free) + 128 words' chars (10 KB). 47 KB LDS -> 3 blocks/CU.
// Compute: thread = (word, hl); R9's sliding window, taps from LDS
// (1 x b128 taps0-7 + 1 x u16 tap8 per char), chars from LDS (broadcast).
// Rationale: vmem route was pinned at ~17 TB/s by the per-CU L1 path
// (64 B/clk); LDS read path is 256 B/clk/CU. Table read once per block
// from L2 instead of once per word.
// ---------------------------------------------------------------------------
__global__ __launch_bounds__(256) void conv_pool(
        const int* __restrict__ chars,
        const ushort* __restrict__ P5,
        const float* __restrict__ b1,
        const float* __restrict__ b3,
        const float* __restrict__ b5,
        ushort* __restrict__ outs) {
    __shared__ uint4 tileq[2304];          // 36864 B table slice
    __shared__ int   chs[128*WW];          // 10240 B chars
    const int t = threadIdx.x;
    const int g = blockIdx.x;              // word group 0..63
    const int s = blockIdx.y;              // h slice   0..31

    {   // stage table slice: 2304 16-B chunks, 9 per thread (v = c/9, k = c%9)
        const char* src = (const char*)P5 + (size_t)s * 144;
        char* dst = (char*)tileq;
        #pragma unroll
        for (int i = 0; i < 9; ++i) {
            int c = i*256 + t;
            int v = c / 9, k = c - 9*v;
            *(uint4*)(dst + v*144 + k*16) =
                *(const uint4*)(src + (size_t)v*4608 + k*16);
        }
        const int* cg = chars + g * 128 * WW;
        #pragma unroll
        for (int i = 0; i < 10; ++i) chs[i*256 + t] = cg[i*256 + t];
    }
    __syncthreads();

    const int hl  = t & 7;
    const int wl0 = t >> 3;                // 0..31
    const char* tile = (const char*)tileq;

    for (int cc = 0; cc < 4; ++cc) {
        const int wl = cc*32 + wl0;
        const int n  = g*128 + wl;
        const int* cw = &chs[wl*WW];

        float acc3[3], acc5[5];
        float m1 = -1e30f, m3 = -1e30f, m5 = -1e30f;
        acc3[0] = 0.f; acc5[0] = 0.f; acc5[1] = 0.f;

        int c_cur = cw[0];
        uint4 q[2]; ushort t8[2];
        q[0]  = *(const uint4*)(tile + c_cur*144 + hl*16);
        t8[0] = *(const ushort*)(tile + c_cur*144 + 128 + hl*2);

        #pragma unroll
        for (int j = 0; j < WW; ++j) {
            const int cur = j & 1, nxt = cur ^ 1;
            if (j + 1 < WW) {               // prefetch char j+1 taps
                int c_n = cw[j+1];
                q[nxt]  = *(const uint4*)(tile + c_n*144 + hl*16);
                t8[nxt] = *(const ushort*)(tile + c_n*144 + 128 + hl*2);
            }
            uint4 qq = q[cur];
            float t0 = blo(qq.x), t1 = bhi(qq.x), t2 = blo(qq.y), t3 = bhi(qq.y);
            float t4 = blo(qq.z), t5 = bhi(qq.z), t6 = blo(qq.w), t7 = bhi(qq.w);
            float t8v = bs2f(t8[cur]);

            // conv1: tap0 -> position j
            m1 = fmaxf(m1, t0);
            // conv3: char j tap(1+tau) -> p = j+1-tau
            if (j + 1 < WW) acc3[(j+1)%3] = t1;       // fresh p=j+1
            acc3[j%3] += t2;                           // p=j
            if (j >= 1) { acc3[(j-1)%3] += t3;         // p=j-1 complete
                          m3 = fmaxf(m3, acc3[(j-1)%3]); }
            // conv5: char j tap(4+tau) -> p = j+2-tau
            if (j + 2 < WW) acc5[(j+2)%5] = t4;       // fresh p=j+2
            if (j + 1 < WW) acc5[(j+1)%5] += t5;      // p=j+1
            acc5[j%5] += t6;                           // p=j
            if (j >= 1) acc5[(j-1)%5] += t7;           // p=j-1
            if (j >= 2) { acc5[(j-2)%5] += t8v;        // p=j-2 complete
                          m5 = fmaxf(m5, acc5[(j-2)%5]); }
        }
        m3 = fmaxf(m3, acc3[(WW-1)%3]);                // p=19
        m5 = fmaxf(m5, acc5[(WW-2)%5]);                // p=18
        m5 = fmaxf(m5, acc5[(WW-1)%5]);                // p=19

        const int h = s*8 + hl;
        ushort* op = outs + (size_t)n * K3 + h;
        op[0*HH] = f2bs(fmaxf(m1 + b1[h], 0.f));
        op[1*HH] = f2bs(fmaxf(m3 + b3[h], 0.f));
        op[2*HH] = f2bs(fmaxf(m5 + b5[h], 0.f));
    }
}

// ---------------------------------------------------------------------------
// K3: out = outs @ lw^T + lb via MFMA 16x16x32. 32m x 32n per wave,
// grid (256, 8) = 2048 single-wave blocks. Double-buffered fragments,
// fully unrolled K.
// A[m][k]: m=lane&15, k=quad*8+j. B[k][n]=lw[n][k]: n=lane&15, k=quad*8+j.
// C/D: col=lane&15, row=quad*4+reg.
// ---------------------------------------------------------------------------
__global__ __launch_bounds__(64) void gemm_out(
        const ushort* __restrict__ outs,   // [8192][768] bf16
        const ushort* __restrict__ lwb,    // [256][768] bf16
        const float* __restrict__ lb,
        float* __restrict__ out) {
    const int lane = threadIdx.x;
    const int m0 = blockIdx.x * 32;
    const int n0 = blockIdx.y * 32;
    const int mrow = lane & 15, quad = lane >> 4;

    f32x4 acc00 = (f32x4){0,0,0,0}, acc01 = (f32x4){0,0,0,0};
    f32x4 acc10 = (f32x4){0,0,0,0}, acc11 = (f32x4){0,0,0,0};
    const ushort* ap = outs + (size_t)(m0 + mrow) * K3 + quad * 8;
    const ushort* bp = lwb  + (size_t)(n0 + mrow) * K3 + quad * 8;

    bf16x8 a0 = *(const bf16x8*)ap, a1 = *(const bf16x8*)(ap + 16*K3);
    bf16x8 b0 = *(const bf16x8*)bp, b1 = *(const bf16x8*)(bp + 16*K3);

    #pragma unroll
    for (int it = 0; it < K3/32; ++it) {
        const int kn = (it + 1 < K3/32) ? (it + 1) * 32 : 0;
        bf16x8 a0n = *(const bf16x8*)(ap + kn);
        bf16x8 a1n = *(const bf16x8*)(ap + 16*K3 + kn);
        bf16x8 b0n = *(const bf16x8*)(bp + kn);
        bf16x8 b1n = *(const bf16x8*)(bp + 16*K3 + kn);
        acc00 = __builtin_amdgcn_mfma_f32_16x16x32_bf16(a0, b0, acc00, 0, 0, 0);
        acc01 = __builtin_amdgcn_mfma_f32_16x16x32_bf16(a0, b1, acc01, 0, 0, 0);
        acc10 = __builtin_amdgcn_mfma_f32_16x16x32_bf16(a1, b0, acc10, 0, 0, 0);
        acc11 = __builtin_amdgcn_mfma_f32_16x16x32_bf16(a1, b1, acc11, 0, 0, 0);
        a0 = a0n; a1 = a1n; b0 = b0n; b1 = b1n;
    }

    #pragma unroll
    for (int i = 0; i < 2; ++i) {
        #pragma unroll
        for (int jn = 0; jn < 2; ++jn) {
            const f32x4 acc = (i==0) ? (jn==0 ? acc00 : acc01)
                                     : (jn==0 ? acc10 : acc11);
            int ncol = n0 + jn*16 + mrow;
            float lbv = lb[ncol];
            #pragma unroll
            for (int r = 0; r < 4; ++r)
                out[(size_t)(m0 + i*16 + quad*4 + r)*HH + ncol] = acc[r] + lbv;
        }
    }
}

// ---------------------------------------------------------------------------
extern "C" void kernel_launch(void* const* d_in, const int* in_sizes, int n_in,
                              void* d_out, int out_size, void* d_ws, size_t ws_size,
                              hipStream_t stream) {
    const int*   chars = (const int*)d_in[0];
    const float* emb   = (const float*)d_in[1];
    const float* w1    = (const float*)d_in[2];
    const float* b1    = (const float*)d_in[3];
    const float* w3    = (const float*)d_in[4];
    const float* b3    = (const float*)d_in[5];
    const float* w5    = (const float*)d_in[6];
    const float* b5    = (const float*)d_in[7];
    const float* lw    = (const float*)d_in[8];
    const float* lb    = (const float*)d_in[9];

    // ws: P5 [256][2304] bf16 (1.18MB) | wTp [64][2304] f32 (0.59MB)
    //   | outs [8192][768] bf16 (12.6MB) | lwb [256][768] bf16 (0.39MB)
    ushort* P5   = (ushort*)d_ws;
    float*  wTp  = (float*)(P5 + VOCAB * UNIT);
    ushort* outs = (ushort*)(wTp + EE * UNIT);
    ushort* lwb  = outs + (size_t)NW * K3;

    prep<<<768, 256, 0, stream>>>(w1, w3, w5, lw, wTp, lwb);
    build_tables<<<dim3(VOCAB/4, 9), 256, 0, stream>>>(emb, wTp, P5);
    conv_pool<<<dim3(NW/128, 32), 256, 0, stream>>>(chars, P5, b1, b3, b5, outs);
    gemm_out<<<dim3(NW/32, HH/32), 64, 0, stream>>>(outs, lwb, lb, (float*)d_out);
}

// Round 11
// 132.883 us; speedup vs baseline: 1.9763x; 1.0117x over previous
//
#include <hip/hip_runtime.h>
#include <hip/hip_bf16.h>

#define WW 20
#define NW 8192         // 64*128 words
#define VOCAB 256
#define EE 64
#define HH 256
#define K3 768          // 3*HH
#define UNIT 2304       // ushorts per vocab unit (P5) = 4608 B, no pad

typedef short bf16x8 __attribute__((ext_vector_type(8)));
typedef float f32x4  __attribute__((ext_vector_type(4)));

__device__ __forceinline__ ushort f2bs(float x) {
    __hip_bfloat16 h = __float2bfloat16(x);
    union { __hip_bfloat16 h; ushort u; } c; c.h = h; return c.u;
}
__device__ __forceinline__ float blo(unsigned u) {
    union { unsigned i; float f; } c; c.i = u << 16; return c.f;
}
__device__ __forceinline__ float bhi(unsigned u) {
    union { unsigned i; float f; } c; c.i = u & 0xffff0000u; return c.f;
}
__device__ __forceinline__ unsigned pack2(float lo, float hi) {
    return (unsigned)f2bs(lo) | ((unsigned)f2bs(hi) << 16);
}

// sliding-window update for one h given this char's 9 taps.
// j is a compile-time constant (fully unrolled caller) so all %3/%5 indices
// and guards fold; a3/a5 stay in registers.
#define STEP(j, qq, t8v, a3, a5, mm1, mm3, mm5) {                        \
    float t0 = blo((qq).x), t1 = bhi((qq).x);                            \
    float t2 = blo((qq).y), t3 = bhi((qq).y);                            \
    float t4 = blo((qq).z), t5 = bhi((qq).z);                            \
    float t6 = blo((qq).w), t7 = bhi((qq).w);                            \
    mm1 = fmaxf(mm1, t0);                                                \
    if ((j) + 1 < WW) a3[((j)+1)%3] = t1;                                \
    a3[(j)%3] += t2;                                                     \
    if ((j) >= 1) { a3[((j)-1)%3] += t3;                                 \
                    mm3 = fmaxf(mm3, a3[((j)-1)%3]); }                   \
    if ((j) + 2 < WW) a5[((j)+2)%5] = t4;                                \
    if ((j) + 1 < WW) a5[((j)+1)%5] += t5;                               \
    a5[(j)%5] += t6;                                                     \
    if ((j) >= 1) a5[((j)-1)%5] += t7;                                   \
    if ((j) >= 2) { a5[((j)-2)%5] += (t8v);                              \
                    mm5 = fmaxf(mm5, a5[((j)-2)%5]); }                   \
}

// ---------------------------------------------------------------------------
// P5 layout (per vocab v, 2304 ushorts = 4608 B): 32 slices s of 144 B:
//   [hl 0..7][taps 0..7] (8 x 16 B rows), then [tap8 for hl 0..7] (16 B).
//   j = s*72 + r;  r<64: tap=r&7, h=s*8+(r>>3);  r>=64: tap=8, h=s*8+(r-64).
// tap8 ushorts for an hl-pair (2p, 2p+1) are one aligned dword at +128+p*4.
// ---------------------------------------------------------------------------

// K0: prep. blocks 0..575: wTp[e][j] f32 (P5 column order);
//          blocks 576..767: lw f32 -> bf16.
__global__ __launch_bounds__(256) void prep(
        const float* __restrict__ w1,
        const float* __restrict__ w3,
        const float* __restrict__ w5,
        const float* __restrict__ lw,
        float* __restrict__ wTp,
        ushort* __restrict__ lwb) {
    const int bid = blockIdx.x;
    if (bid < 576) {
        int idx = bid * 256 + threadIdx.x;      // = e*2304 + j, 147456 total
        int e = idx / UNIT;
        int j = idx - e * UNIT;
        int s = j / 72, r = j - s * 72;
        int tap, h;
        if (r < 64) { tap = r & 7; h = s*8 + (r >> 3); }
        else        { tap = 8;     h = s*8 + (r - 64); }
        float v;
        if (tap == 0)      v = w1[h*EE + e];
        else if (tap <= 3) v = w3[(h*EE + e)*3 + (tap-1)];
        else               v = w5[(h*EE + e)*5 + (tap-4)];
        wTp[idx] = v;
    } else {
        int i = ((bid - 576) * 256 + threadIdx.x) * 4;
        float4 v = *(const float4*)(lw + i);
        ushort4 o4;
        o4.x = f2bs(v.x); o4.y = f2bs(v.y); o4.z = f2bs(v.z); o4.w = f2bs(v.w);
        *(ushort4*)(lwb + i) = o4;
    }
}

// K1: P5[v][j] = sum_e emb[v][e] * wTp[e][j]. 4 vocab rows per block,
// grid (64, 9) x 256 thr. Coalesced streaming reads/writes.
__global__ __launch_bounds__(256) void build_tables(
        const float* __restrict__ emb,
        const float* __restrict__ wTp,
        ushort* __restrict__ P5) {
    __shared__ float emb_s[4][EE];
    const int v0 = blockIdx.x * 4;
    const int j  = blockIdx.y * 256 + threadIdx.x;
    const int t  = threadIdx.x;
    emb_s[t >> 6][t & 63] = emb[v0*EE + t];
    __syncthreads();

    float a0 = 0.f, a1 = 0.f, a2 = 0.f, a3 = 0.f;
    const float* wp = wTp + j;
    #pragma unroll 8
    for (int e = 0; e < EE; ++e) {
        float w = wp[e * UNIT];
        a0 += emb_s[0][e] * w; a1 += emb_s[1][e] * w;
        a2 += emb_s[2][e] * w; a3 += emb_s[3][e] * w;
    }
    P5[(size_t)(v0+0)*UNIT + j] = f2bs(a0);
    P5[(size_t)(v0+1)*UNIT + j] = f2bs(a1);
    P5[(size_t)(v0+2)*UNIT + j] = f2bs(a2);
    P5[(size_t)(v0+3)*UNIT + j] = f2bs(a3);
}

// ---------------------------------------------------------------------------
// K2: conv+relu+maxpool, LDS-staged table (R10-proven path), hl-PAIR threads.
// Block = (128 words, 8-h slice). Thread = (word, hl-pair p): owns h0=s*8+2p
// and h0+1. Per char: 2 x ds_read_b128 (taps0-7 both h) + 1 x ds_read_b32
// (tap8 pair) -- replaces R10's per-h b128+u16: 12 LDS cyc per h-char vs 18.
// cc loop 2 (64 word-lanes x 4 pairs per wave-pass). Occupancy LDS-bound
// (47 KB -> 3 blocks/CU), so the extra VGPRs are free.
// Bias after max; ReLU at the end; packed u32 stores (h0 even).
// ---------------------------------------------------------------------------
__global__ __launch_bounds__(256) void conv_pool(
        const int* __restrict__ chars,
        const ushort* __restrict__ P5,
        const float* __restrict__ b1,
        const float* __restrict__ b3,
        const float* __restrict__ b5,
        ushort* __restrict__ outs) {
    __shared__ uint4 tileq[2304];          // 36864 B table slice
    __shared__ int   chs[128*WW];          // 10240 B chars
    const int t = threadIdx.x;
    const int g = blockIdx.x;              // word group 0..63
    const int s = blockIdx.y;              // h slice   0..31

    {   // stage table slice: 2304 16-B chunks, 9 per thread (v = c/9, k = c%9)
        const char* src = (const char*)P5 + (size_t)s * 144;
        char* dst = (char*)tileq;
        #pragma unroll
        for (int i = 0; i < 9; ++i) {
            int c = i*256 + t;
            int v = c / 9, k = c - 9*v;
            *(uint4*)(dst + v*144 + k*16) =
                *(const uint4*)(src + (size_t)v*4608 + k*16);
        }
        const int* cg = chars + g * 128 * WW;
        #pragma unroll
        for (int i = 0; i < 10; ++i) chs[i*256 + t] = cg[i*256 + t];
    }
    __syncthreads();

    const int p   = t & 3;                 // hl pair 0..3
    const int wl0 = t >> 2;                // word lane 0..63
    const char* tile = (const char*)tileq;
    const int h0  = s*8 + p*2;
    const float2 bb1 = *(const float2*)(b1 + h0);
    const float2 bb3 = *(const float2*)(b3 + h0);
    const float2 bb5 = *(const float2*)(b5 + h0);

    #pragma unroll
    for (int cc = 0; cc < 2; ++cc) {
        const int wl = cc*64 + wl0;
        const int n  = g*128 + wl;
        const int* cw = &chs[wl*WW];

        float a3[2][3], a5[2][5], m1[2], m3[2], m5[2];
        #pragma unroll
        for (int i = 0; i < 2; ++i) {
            a3[i][0] = 0.f; a5[i][0] = 0.f; a5[i][1] = 0.f;
            m1[i] = -1e30f; m3[i] = -1e30f; m5[i] = -1e30f;
        }

        uint4 qa[2], qb[2]; unsigned t8[2];
        {   // preload char 0
            int c0 = cw[0];
            qa[0] = *(const uint4*)(tile + c0*144 + p*32);
            qb[0] = *(const uint4*)(tile + c0*144 + p*32 + 16);
            t8[0] = *(const unsigned*)(tile + c0*144 + 128 + p*4);
        }

        #pragma unroll
        for (int j = 0; j < WW; ++j) {
            const int cur = j & 1, nxt = cur ^ 1;
            if (j + 1 < WW) {               // prefetch char j+1
                int cn = cw[j+1];
                qa[nxt] = *(const uint4*)(tile + cn*144 + p*32);
                qb[nxt] = *(const uint4*)(tile + cn*144 + p*32 + 16);
                t8[nxt] = *(const unsigned*)(tile + cn*144 + 128 + p*4);
            }
            float t8lo = blo(t8[cur]), t8hi = bhi(t8[cur]);
            STEP(j, qa[cur], t8lo, a3[0], a5[0], m1[0], m3[0], m5[0]);
            STEP(j, qb[cur], t8hi, a3[1], a5[1], m1[1], m3[1], m5[1]);
        }
        #pragma unroll
        for (int i = 0; i < 2; ++i) {
            m3[i] = fmaxf(m3[i], a3[i][(WW-1)%3]);     // p=19
            m5[i] = fmaxf(m5[i], a5[i][(WW-2)%5]);     // p=18
            m5[i] = fmaxf(m5[i], a5[i][(WW-1)%5]);     // p=19
        }

        unsigned* op = (unsigned*)(outs + (size_t)n * K3 + h0);
        op[0*(HH/2)] = pack2(fmaxf(m1[0]+bb1.x, 0.f), fmaxf(m1[1]+bb1.y, 0.f));
        op[1*(HH/2)] = pack2(fmaxf(m3[0]+bb3.x, 0.f), fmaxf(m3[1]+bb3.y, 0.f));
        op[2*(HH/2)] = pack2(fmaxf(m5[0]+bb5.x, 0.f), fmaxf(m5[1]+bb5.y, 0.f));
    }
}

// ---------------------------------------------------------------------------
// K3: out = outs @ lw^T + lb via MFMA 16x16x32. 32m x 32n per wave,
// grid (256, 8) = 2048 single-wave blocks. Double-buffered fragments,
// fully unrolled K.
// A[m][k]: m=lane&15, k=quad*8+j. B[k][n]=lw[n][k]: n=lane&15, k=quad*8+j.
// C/D: col=lane&15, row=quad*4+reg.
// ---------------------------------------------------------------------------
__global__ __launch_bounds__(64) void gemm_out(
        const ushort* __restrict__ outs,   // [8192][768] bf16
        const ushort* __restrict__ lwb,    // [256][768] bf16
        const float* __restrict__ lb,
        float* __restrict__ out) {
    const int lane = threadIdx.x;
    const int m0 = blockIdx.x * 32;
    const int n0 = blockIdx.y * 32;
    const int mrow = lane & 15, quad = lane >> 4;

    f32x4 acc00 = (f32x4){0,0,0,0}, acc01 = (f32x4){0,0,0,0};
    f32x4 acc10 = (f32x4){0,0,0,0}, acc11 = (f32x4){0,0,0,0};
    const ushort* ap = outs + (size_t)(m0 + mrow) * K3 + quad * 8;
    const ushort* bp = lwb  + (size_t)(n0 + mrow) * K3 + quad * 8;

    bf16x8 a0 = *(const bf16x8*)ap, a1 = *(const bf16x8*)(ap + 16*K3);
    bf16x8 b0 = *(const bf16x8*)bp, b1 = *(const bf16x8*)(bp + 16*K3);

    #pragma unroll
    for (int it = 0; it < K3/32; ++it) {
        const int kn = (it + 1 < K3/32) ? (it + 1) * 32 : 0;
        bf16x8 a0n = *(const bf16x8*)(ap + kn);
        bf16x8 a1n = *(const bf16x8*)(ap + 16*K3 + kn);
        bf16x8 b0n = *(const bf16x8*)(bp + kn);
        bf16x8 b1n = *(const bf16x8*)(bp + 16*K3 + kn);
        acc00 = __builtin_amdgcn_mfma_f32_16x16x32_bf16(a0, b0, acc00, 0, 0, 0);
        acc01 = __builtin_amdgcn_mfma_f32_16x16x32_bf16(a0, b1, acc01, 0, 0, 0);
        acc10 = __builtin_amdgcn_mfma_f32_16x16x32_bf16(a1, b0, acc10, 0, 0, 0);
        acc11 = __builtin_amdgcn_mfma_f32_16x16x32_bf16(a1, b1, acc11, 0, 0, 0);
        a0 = a0n; a1 = a1n; b0 = b0n; b1 = b1n;
    }

    #pragma unroll
    for (int i = 0; i < 2; ++i) {
        #pragma unroll
        for (int jn = 0; jn < 2; ++jn) {
            const f32x4 acc = (i==0) ? (jn==0 ? acc00 : acc01)
                                     : (jn==0 ? acc10 : acc11);
            int ncol = n0 + jn*16 + mrow;
            float lbv = lb[ncol];
            #pragma unroll
            for (int r = 0; r < 4; ++r)
                out[(size_t)(m0 + i*16 + quad*4 + r)*HH + ncol] = acc[r] + lbv;
        }
    }
}

// ---------------------------------------------------------------------------
extern "C" void kernel_launch(void* const* d_in, const int* in_sizes, int n_in,
                              void* d_out, int out_size, void* d_ws, size_t ws_size,
                              hipStream_t stream) {
    const int*   chars = (const int*)d_in[0];
    const float* emb   = (const float*)d_in[1];
    const float* w1    = (const float*)d_in[2];
    const float* b1    = (const float*)d_in[3];
    const float* w3    = (const float*)d_in[4];
    const float* b3    = (const float*)d_in[5];
    const float* w5    = (const float*)d_in[6];
    const float* b5    = (const float*)d_in[7];
    const float* lw    = (const float*)d_in[8];
    const float* lb    = (const float*)d_in[9];

    // ws: P5 [256][2304] bf16 (1.18MB) | wTp [64][2304] f32 (0.59MB)
    //   | outs [8192][768] bf16 (12.6MB) | lwb [256][768] bf16 (0.39MB)
    ushort* P5   = (ushort*)d_ws;
    float*  wTp  = (float*)(P5 + VOCAB * UNIT);
    ushort* outs = (ushort*)(wTp + EE * UNIT);
    ushort* lwb  = outs + (size_t)NW * K3;

    prep<<<768, 256, 0, stream>>>(w1, w3, w5, lw, wTp, lwb);
    build_tables<<<dim3(VOCAB/4, 9), 256, 0, stream>>>(emb, wTp, P5);
    conv_pool<<<dim3(NW/128, 32), 256, 0, stream>>>(chars, P5, b1, b3, b5, outs);
    gemm_out<<<dim3(NW/32, HH/32), 64, 0, stream>>>(outs, lwb, lb, (float*)d_out);
}